// Round 1
// baseline (160.774 us; speedup 1.0000x reference)
//
#include <hip/hip_runtime.h>

#define N 4096
#define K 8
#define BI 8   // rows of A per block in the pair kernel

__device__ __forceinline__ float fast_exp2(float x) {
#if __has_builtin(__builtin_amdgcn_exp2f)
    return __builtin_amdgcn_exp2f(x);
#else
    return exp2f(x);
#endif
}
__device__ __forceinline__ float fast_log2(float x) {
#if __has_builtin(__builtin_amdgcn_logf)
    return __builtin_amdgcn_logf(x);
#else
    return log2f(x);
#endif
}
__device__ __forceinline__ float fast_sqrt(float x) {
#if __has_builtin(__builtin_amdgcn_sqrtf)
    return __builtin_amdgcn_sqrtf(x);
#else
    return sqrtf(x);
#endif
}

// Pass 1: ZsT[n][k] = softmax_k(Z[:,n]); U[k][k'] = sum_n ZsT[n][k]*exp(C[n][k']);
//         S[k'] = sum_n exp(C[n][k']).   (T = U/S computed later.)
__global__ __launch_bounds__(256) void prep_stats(
    const float* __restrict__ Z, const float* __restrict__ C,
    float* __restrict__ ZsT, float* __restrict__ U, float* __restrict__ S)
{
    const int n = blockIdx.x * 256 + threadIdx.x;
    const float L2E = 1.44269504f;

    float z[K];
#pragma unroll
    for (int k = 0; k < K; ++k) z[k] = Z[k * N + n];
    float zmax = z[0];
#pragma unroll
    for (int k = 1; k < K; ++k) zmax = fmaxf(zmax, z[k]);
    float zs[K];
    float zsum = 0.f;
#pragma unroll
    for (int k = 0; k < K; ++k) { zs[k] = fast_exp2((z[k] - zmax) * L2E); zsum += zs[k]; }
    const float inv = 1.f / zsum;
#pragma unroll
    for (int k = 0; k < K; ++k) zs[k] *= inv;
    // vectorized store of this node's softmax row
    float4* zst_p = (float4*)(ZsT + (size_t)n * K);
    zst_p[0] = make_float4(zs[0], zs[1], zs[2], zs[3]);
    zst_p[1] = make_float4(zs[4], zs[5], zs[6], zs[7]);

    // exp of this node's C row
    const float4* c_p = (const float4*)(C + (size_t)n * K);
    const float4 c0 = c_p[0], c1 = c_p[1];
    float e[K];
    e[0] = fast_exp2(c0.x * L2E); e[1] = fast_exp2(c0.y * L2E);
    e[2] = fast_exp2(c0.z * L2E); e[3] = fast_exp2(c0.w * L2E);
    e[4] = fast_exp2(c1.x * L2E); e[5] = fast_exp2(c1.y * L2E);
    e[6] = fast_exp2(c1.z * L2E); e[7] = fast_exp2(c1.w * L2E);

    float u[K * K];
#pragma unroll
    for (int a = 0; a < K; ++a)
#pragma unroll
        for (int b = 0; b < K; ++b) u[a * K + b] = zs[a] * e[b];

    // wave(64)-level shuffle reduction of 64 u-values + 8 s-values
#pragma unroll
    for (int v = 0; v < K * K; ++v) {
        float x = u[v];
        for (int off = 32; off > 0; off >>= 1) x += __shfl_down(x, off, 64);
        u[v] = x;
    }
#pragma unroll
    for (int v = 0; v < K; ++v) {
        float x = e[v];
        for (int off = 32; off > 0; off >>= 1) x += __shfl_down(x, off, 64);
        e[v] = x;
    }

    __shared__ float red[4][72];
    const int lane = threadIdx.x & 63, wid = threadIdx.x >> 6;
    if (lane == 0) {
#pragma unroll
        for (int v = 0; v < K * K; ++v) red[wid][v] = u[v];
#pragma unroll
        for (int v = 0; v < K; ++v) red[wid][64 + v] = e[v];
    }
    __syncthreads();
    const int t = threadIdx.x;
    if (t < 72) {
        const float sum = red[0][t] + red[1][t] + red[2][t] + red[3][t];
        if (t < 64) atomicAdd(&U[t], sum);
        else        atomicAdd(&S[t - 64], sum);
    }
}

// Pass 2: M[n][k] = sum_k' (U[k][k']/S[k']) * ZsT[n][k']
__global__ __launch_bounds__(256) void prep_M(
    const float* __restrict__ ZsT, const float* __restrict__ U,
    const float* __restrict__ S, float* __restrict__ M)
{
    const int n = blockIdx.x * 256 + threadIdx.x;
    const float4* zst_p = (const float4*)(ZsT + (size_t)n * K);
    const float4 z0 = zst_p[0], z1 = zst_p[1];
    float w[K];
    w[0] = z0.x / S[0]; w[1] = z0.y / S[1]; w[2] = z0.z / S[2]; w[3] = z0.w / S[3];
    w[4] = z1.x / S[4]; w[5] = z1.y / S[5]; w[6] = z1.z / S[6]; w[7] = z1.w / S[7];
    float m[K];
#pragma unroll
    for (int k = 0; k < K; ++k) {
        float acc = 0.f;
#pragma unroll
        for (int kk = 0; kk < K; ++kk) acc = fmaf(U[k * K + kk], w[kk], acc);
        m[k] = acc;
    }
    float4* m_p = (float4*)(M + (size_t)n * K);
    m_p[0] = make_float4(m[0], m[1], m[2], m[3]);
    m_p[1] = make_float4(m[4], m[5], m[6], m[7]);
}

// Pass 3: LL = sum_{i!=j} theta_ij*A_ij - softplus(theta_ij)
// theta_ij = beta_i + beta_j - a * || M[i]-M[j]+1e-6 ||
__global__ __launch_bounds__(256) void pair_ll(
    const float* __restrict__ A, const float* __restrict__ beta,
    const float* __restrict__ a_ptr, const float* __restrict__ M,
    float* __restrict__ out)
{
    const int t = threadIdx.x;
    const int i0 = blockIdx.x * BI;

    __shared__ __align__(16) float Mi_s[BI * K];
    __shared__ float beta_s[BI];
    if (t < BI * K) Mi_s[t] = M[(size_t)i0 * K + t] + 1e-6f;   // fold the +1e-6 shift into M_i
    if (t >= 64 && t < 64 + BI) beta_s[t - 64] = beta[i0 + t - 64];
    __syncthreads();

    const float aa = a_ptr[0];
    const float L2E = 1.44269504f;
    const float LN2 = 0.69314718f;

    float acc = 0.f;
    for (int j0 = 0; j0 < N; j0 += 256) {
        const int j = j0 + t;
        const float4* mj_p = (const float4*)(M + (size_t)j * K);
        const float4 mj0 = mj_p[0];
        const float4 mj1 = mj_p[1];
        const float bj = beta[j];
#pragma unroll
        for (int ii = 0; ii < BI; ++ii) {
            const int gi = i0 + ii;
            const float av = A[(size_t)gi * N + j];
            const float4 mi0 = *(const float4*)(&Mi_s[ii * K]);      // LDS broadcast (b128)
            const float4 mi1 = *(const float4*)(&Mi_s[ii * K + 4]);
            const float d0 = mi0.x - mj0.x, d1 = mi0.y - mj0.y;
            const float d2 = mi0.z - mj0.z, d3 = mi0.w - mj0.w;
            const float d4 = mi1.x - mj1.x, d5 = mi1.y - mj1.y;
            const float d6 = mi1.z - mj1.z, d7 = mi1.w - mj1.w;
            float ss = d0 * d0;
            ss = fmaf(d1, d1, ss); ss = fmaf(d2, d2, ss); ss = fmaf(d3, d3, ss);
            ss = fmaf(d4, d4, ss); ss = fmaf(d5, d5, ss); ss = fmaf(d6, d6, ss);
            ss = fmaf(d7, d7, ss);
            const float dist  = fast_sqrt(ss);
            const float theta = fmaf(-aa, dist, beta_s[ii] + bj);
            // softplus: theta <= ~10 here, so log(1+exp(theta)) is overflow-safe
            const float ex = fast_exp2(theta * L2E);
            const float sp = LN2 * fast_log2(1.f + ex);
            const float contrib = fmaf(theta, av, -sp);
            acc += (gi == j) ? 0.f : contrib;   // zero the diagonal, branch-free
        }
    }

    // block reduction -> one atomic per block
    for (int off = 32; off > 0; off >>= 1) acc += __shfl_down(acc, off, 64);
    __shared__ float wsum[4];
    const int lane = t & 63, wid = t >> 6;
    if (lane == 0) wsum[wid] = acc;
    __syncthreads();
    if (t == 0) atomicAdd(out, wsum[0] + wsum[1] + wsum[2] + wsum[3]);
}

extern "C" void kernel_launch(void* const* d_in, const int* in_sizes, int n_in,
                              void* d_out, int out_size, void* d_ws, size_t ws_size,
                              hipStream_t stream)
{
    const float* A    = (const float*)d_in[0];   // [N,N]
    const float* beta = (const float*)d_in[1];   // [N]
    const float* a    = (const float*)d_in[2];   // [1]
    const float* Z    = (const float*)d_in[3];   // [K,N]
    const float* C    = (const float*)d_in[4];   // [N,K]
    float* out = (float*)d_out;                  // scalar LL

    float* ws  = (float*)d_ws;
    float* ZsT = ws;                 // N*K floats
    float* M   = ws + (size_t)N * K; // N*K floats
    float* U   = ws + (size_t)2 * N * K; // 64 floats
    float* S   = U + 64;                 // 8 floats

    hipMemsetAsync(out, 0, sizeof(float), stream);
    hipMemsetAsync(U, 0, 72 * sizeof(float), stream);  // U + S

    prep_stats<<<N / 256, 256, 0, stream>>>(Z, C, ZsT, U, S);
    prep_M<<<N / 256, 256, 0, stream>>>(ZsT, U, S, M);
    pair_ll<<<N / BI, 256, 0, stream>>>(A, beta, a, M, out);
}

// Round 2
// 132.621 us; speedup vs baseline: 1.2123x; 1.2123x over previous
//
#include <hip/hip_runtime.h>

#define N 4096
#define K 8
#define BI 8            // rows of A per block in the pair kernel
#define JT 4            // j-tiles
#define JTILE (N / JT)  // 1024 columns per block (256 threads * float4)

__device__ __forceinline__ float fast_exp2(float x) { return __builtin_amdgcn_exp2f(x); }
__device__ __forceinline__ float fast_log2(float x) { return __builtin_amdgcn_logf(x); }
__device__ __forceinline__ float fast_sqrt(float x) { return __builtin_amdgcn_sqrtf(x); }

// ---------------------------------------------------------------------------
// Pass 1: ZsT[n][k] = softmax_k(Z[:,n]);  U[k][k'] = sum_n ZsT[n][k]*exp(C[n][k']);
//         S[k'] = sum_n exp(C[n][k']).
// Reduction via LDS staging (no 72-value shuffle web -> no VGPR spills).
// ---------------------------------------------------------------------------
__global__ __launch_bounds__(256) void prep_stats(
    const float* __restrict__ Z, const float* __restrict__ C,
    float* __restrict__ ZsT, float* __restrict__ U, float* __restrict__ S)
{
    const int t = threadIdx.x;
    const int n = blockIdx.x * 256 + t;
    const float L2E = 1.44269504f;

    __shared__ float zsL[256 * K];
    __shared__ float eL[256 * K];

    float z[K];
#pragma unroll
    for (int k = 0; k < K; ++k) z[k] = Z[k * N + n];   // coalesced column reads
    float zmax = z[0];
#pragma unroll
    for (int k = 1; k < K; ++k) zmax = fmaxf(zmax, z[k]);
    float zs[K];
    float zsum = 0.f;
#pragma unroll
    for (int k = 0; k < K; ++k) { zs[k] = fast_exp2((z[k] - zmax) * L2E); zsum += zs[k]; }
    const float inv = 1.f / zsum;
#pragma unroll
    for (int k = 0; k < K; ++k) zs[k] *= inv;

    float4* zst_p = (float4*)(ZsT + (size_t)n * K);
    zst_p[0] = make_float4(zs[0], zs[1], zs[2], zs[3]);
    zst_p[1] = make_float4(zs[4], zs[5], zs[6], zs[7]);

    const float4* c_p = (const float4*)(C + (size_t)n * K);
    const float4 c0 = c_p[0], c1 = c_p[1];
    float e[K];
    e[0] = fast_exp2(c0.x * L2E); e[1] = fast_exp2(c0.y * L2E);
    e[2] = fast_exp2(c0.z * L2E); e[3] = fast_exp2(c0.w * L2E);
    e[4] = fast_exp2(c1.x * L2E); e[5] = fast_exp2(c1.y * L2E);
    e[6] = fast_exp2(c1.z * L2E); e[7] = fast_exp2(c1.w * L2E);

#pragma unroll
    for (int k = 0; k < K; ++k) { zsL[t * K + k] = zs[k]; eL[t * K + k] = e[k]; }
    __syncthreads();

    // 64 threads own one (a,b) cell each; 8 more own S[b]. Same-address
    // broadcast within 8-lane groups -> conflict-free LDS reads.
    if (t < 64) {
        const int a = t >> 3, b = t & 7;
        float s = 0.f;
        for (int nn = 0; nn < 256; ++nn)
            s = fmaf(zsL[nn * K + a], eL[nn * K + b], s);
        atomicAdd(&U[t], s);
    } else if (t < 72) {
        const int b = t - 64;
        float s = 0.f;
        for (int nn = 0; nn < 256; ++nn) s += eL[nn * K + b];
        atomicAdd(&S[b], s);
    }
}

// ---------------------------------------------------------------------------
// Pass 2: M[n][k] = sum_k' (U[k][k']/S[k']) * ZsT[n][k'].
// Also subtracts the exact diagonal contribution from `out`, so pair_ll can
// sum over ALL pairs with no per-pair diagonal test:
//   theta_ii = 2*beta_i - a*sqrt(8)*1e-6;  diag = theta_ii*A_ii - softplus(theta_ii)
// ---------------------------------------------------------------------------
__global__ __launch_bounds__(256) void prep_M(
    const float* __restrict__ ZsT, const float* __restrict__ U,
    const float* __restrict__ S, const float* __restrict__ A,
    const float* __restrict__ beta, const float* __restrict__ a_ptr,
    float* __restrict__ M, float* __restrict__ out)
{
    const int t = threadIdx.x;
    const int n = blockIdx.x * 256 + t;
    const float L2E = 1.44269504f;
    const float LN2 = 0.69314718f;

    __shared__ float UL[64];
    __shared__ float SinvL[8];
    if (t < 64) UL[t] = U[t];
    else if (t < 72) SinvL[t - 64] = 1.f / S[t - 64];
    __syncthreads();

    const float4* zst_p = (const float4*)(ZsT + (size_t)n * K);
    const float4 z0 = zst_p[0], z1 = zst_p[1];
    float w[K];
    w[0] = z0.x * SinvL[0]; w[1] = z0.y * SinvL[1]; w[2] = z0.z * SinvL[2]; w[3] = z0.w * SinvL[3];
    w[4] = z1.x * SinvL[4]; w[5] = z1.y * SinvL[5]; w[6] = z1.z * SinvL[6]; w[7] = z1.w * SinvL[7];
    float m[K];
#pragma unroll
    for (int k = 0; k < K; ++k) {
        float acc = 0.f;
#pragma unroll
        for (int kk = 0; kk < K; ++kk) acc = fmaf(UL[k * K + kk], w[kk], acc);
        m[k] = acc;
    }
    float4* m_p = (float4*)(M + (size_t)n * K);
    m_p[0] = make_float4(m[0], m[1], m[2], m[3]);
    m_p[1] = make_float4(m[4], m[5], m[6], m[7]);

    // exact diagonal contribution (to be subtracted)
    const float av = A[(size_t)n * N + n];
    const float theta = fmaf(-a_ptr[0], 2.8284271247e-6f, 2.f * beta[n]);
    const float ex = fast_exp2(theta * L2E);
    const float sp = LN2 * fast_log2(1.f + ex);
    float d = fmaf(theta, av, -sp);   // this node's diagonal term

    // block-reduce then one atomic
    for (int off = 32; off > 0; off >>= 1) d += __shfl_down(d, off, 64);
    __shared__ float wsum[4];
    const int lane = t & 63, wid = t >> 6;
    if (lane == 0) wsum[wid] = d;
    __syncthreads();
    if (t == 0) atomicAdd(out, -(wsum[0] + wsum[1] + wsum[2] + wsum[3]));
}

// ---------------------------------------------------------------------------
// Pass 3: LL += sum_{all i,j} theta_ij*A_ij - softplus(theta_ij)
// theta_ij = beta_i + beta_j - a * sqrt(|Mi'|^2 + |Mj|^2 - 2 Mi'.Mj),
// Mi' = M[i] + 1e-6 (the reference's shift folded into the i side).
// Grid: (N/BI) x JT blocks; thread handles 4 consecutive j via float4 loads.
// ---------------------------------------------------------------------------
__global__ __launch_bounds__(256) void pair_ll(
    const float* __restrict__ A, const float* __restrict__ beta,
    const float* __restrict__ a_ptr, const float* __restrict__ M,
    float* __restrict__ out)
{
    const int t = threadIdx.x;
    const int i0 = blockIdx.x * BI;
    const int j = blockIdx.y * JTILE + t * 4;

    __shared__ __align__(16) float twoMi[BI][K];
    __shared__ float mi2_s[BI];
    __shared__ float beta_s[BI];
    if (t < BI) {
        const float4* mp = (const float4*)(M + (size_t)(i0 + t) * K);
        const float4 a0 = mp[0], a1 = mp[1];
        float v[K] = { a0.x + 1e-6f, a0.y + 1e-6f, a0.z + 1e-6f, a0.w + 1e-6f,
                       a1.x + 1e-6f, a1.y + 1e-6f, a1.z + 1e-6f, a1.w + 1e-6f };
        float s2 = 0.f;
#pragma unroll
        for (int k = 0; k < K; ++k) { s2 = fmaf(v[k], v[k], s2); twoMi[t][k] = 2.f * v[k]; }
        mi2_s[t] = s2;
        beta_s[t] = beta[i0 + t];
    }
    __syncthreads();

    const float aa = a_ptr[0];
    const float L2E = 1.44269504f;
    const float LN2 = 0.69314718f;

    // M and beta for this thread's 4 columns (j fixed for the whole block)
    float4 mj0[4], mj1[4];
    float mj2[4];
#pragma unroll
    for (int c = 0; c < 4; ++c) {
        const float4* mp = (const float4*)(M + (size_t)(j + c) * K);
        mj0[c] = mp[0]; mj1[c] = mp[1];
        float s2 = mj0[c].x * mj0[c].x;
        s2 = fmaf(mj0[c].y, mj0[c].y, s2); s2 = fmaf(mj0[c].z, mj0[c].z, s2);
        s2 = fmaf(mj0[c].w, mj0[c].w, s2); s2 = fmaf(mj1[c].x, mj1[c].x, s2);
        s2 = fmaf(mj1[c].y, mj1[c].y, s2); s2 = fmaf(mj1[c].z, mj1[c].z, s2);
        s2 = fmaf(mj1[c].w, mj1[c].w, s2);
        mj2[c] = s2;
    }
    const float4 bj4 = *(const float4*)(beta + j);
    const float bj[4] = { bj4.x, bj4.y, bj4.z, bj4.w };

    float acc = 0.f;
#pragma unroll
    for (int ii = 0; ii < BI; ++ii) {
        const float4 av = *(const float4*)(A + (size_t)(i0 + ii) * N + j);
        const float4 tm0 = *(const float4*)(&twoMi[ii][0]);   // LDS b128 broadcast
        const float4 tm1 = *(const float4*)(&twoMi[ii][4]);
        const float base = mi2_s[ii];
        const float bi = beta_s[ii];
        const float avc[4] = { av.x, av.y, av.z, av.w };
#pragma unroll
        for (int c = 0; c < 4; ++c) {
            float ss = base + mj2[c];
            ss = fmaf(-tm0.x, mj0[c].x, ss); ss = fmaf(-tm0.y, mj0[c].y, ss);
            ss = fmaf(-tm0.z, mj0[c].z, ss); ss = fmaf(-tm0.w, mj0[c].w, ss);
            ss = fmaf(-tm1.x, mj1[c].x, ss); ss = fmaf(-tm1.y, mj1[c].y, ss);
            ss = fmaf(-tm1.z, mj1[c].z, ss); ss = fmaf(-tm1.w, mj1[c].w, ss);
            ss = fmaxf(ss, 0.f);                       // cancellation guard
            const float dist = fast_sqrt(ss);
            const float theta = fmaf(-aa, dist, bi + bj[c]);
            const float ex = fast_exp2(theta * L2E);   // theta <= ~10: safe
            const float sp = LN2 * fast_log2(1.f + ex);
            acc = fmaf(theta, avc[c], acc);
            acc -= sp;
        }
    }

    for (int off = 32; off > 0; off >>= 1) acc += __shfl_down(acc, off, 64);
    __shared__ float wsum[4];
    const int lane = t & 63, wid = t >> 6;
    if (lane == 0) wsum[wid] = acc;
    __syncthreads();
    if (t == 0) atomicAdd(out, wsum[0] + wsum[1] + wsum[2] + wsum[3]);
}

extern "C" void kernel_launch(void* const* d_in, const int* in_sizes, int n_in,
                              void* d_out, int out_size, void* d_ws, size_t ws_size,
                              hipStream_t stream)
{
    const float* A    = (const float*)d_in[0];   // [N,N]
    const float* beta = (const float*)d_in[1];   // [N]
    const float* a    = (const float*)d_in[2];   // [1]
    const float* Z    = (const float*)d_in[3];   // [K,N]
    const float* C    = (const float*)d_in[4];   // [N,K]
    float* out = (float*)d_out;

    float* ws  = (float*)d_ws;
    float* ZsT = ws;                     // N*K floats
    float* M   = ws + (size_t)N * K;     // N*K floats
    float* U   = ws + (size_t)2 * N * K; // 64 floats
    float* S   = U + 64;                 // 8 floats (contiguous with U)

    hipMemsetAsync(out, 0, sizeof(float), stream);
    hipMemsetAsync(U, 0, 72 * sizeof(float), stream);   // U + S in one node

    prep_stats<<<N / 256, 256, 0, stream>>>(Z, C, ZsT, U, S);
    prep_M<<<N / 256, 256, 0, stream>>>(ZsT, U, S, A, beta, a, M, out);

    dim3 grid(N / BI, JT);
    pair_ll<<<grid, 256, 0, stream>>>(A, beta, a, M, out);
}